// Round 8
// baseline (4775.122 us; speedup 1.0000x reference)
//
#include <hip/hip_runtime.h>

typedef unsigned int uint;

enum { ACT_RELU=0, ACT_SIGMOID=1, ACT_RESBN=2 };

// ---------------- fused GEMM (f32): C = act(A @ W + bias) [+BN/residual] -----
// A:[M,K] row-major, W:[K,N] row-major. Optional second store C2 (same values).
// tile 64x64, BK=16, 256 threads, 4x4 acc/thread. M%64==0, K%16==0.
template<int ACT>
__global__ __launch_bounds__(256) void gemm_fused(
    const float* __restrict__ A, const float* __restrict__ W,
    const float* __restrict__ bias, float* __restrict__ C,
    float* __restrict__ C2, const float* __restrict__ R,
    const float* __restrict__ gamma, const float* __restrict__ beta,
    int M, int N, int K)
{
    __shared__ float As[16][68];
    __shared__ float Bs[16][68];
    const int tx = threadIdx.x, ty = threadIdx.y;
    const int tid = ty*16 + tx;
    const int row0 = blockIdx.y*64, col0 = blockIdx.x*64;
    float acc[4][4] = {};
    for (int k0 = 0; k0 < K; k0 += 16) {
        #pragma unroll
        for (int t = tid; t < 1024; t += 256) {
            int r = t >> 4, c = t & 15;
            As[c][r] = A[(size_t)(row0+r)*K + k0 + c];
        }
        #pragma unroll
        for (int t = tid; t < 1024; t += 256) {
            int kr = t >> 6, c = t & 63;
            int gc = col0 + c;
            Bs[kr][c] = (gc < N) ? W[(size_t)(k0+kr)*N + gc] : 0.f;
        }
        __syncthreads();
        #pragma unroll
        for (int kk = 0; kk < 16; kk++) {
            float a[4], b[4];
            #pragma unroll
            for (int i = 0; i < 4; i++) a[i] = As[kk][ty*4+i];
            #pragma unroll
            for (int j = 0; j < 4; j++) b[j] = Bs[kk][tx*4+j];
            #pragma unroll
            for (int i = 0; i < 4; i++)
                #pragma unroll
                for (int j = 0; j < 4; j++)
                    acc[i][j] += a[i]*b[j];
        }
        __syncthreads();
    }
    const float INVS = 0.99999500003749968f; // 1/sqrt(1+1e-5)
    #pragma unroll
    for (int i = 0; i < 4; i++) {
        int r = row0 + ty*4 + i;
        #pragma unroll
        for (int j = 0; j < 4; j++) {
            int c = col0 + tx*4 + j;
            if (c < N) {
                float v = acc[i][j] + bias[c];
                if (ACT == ACT_RELU) {
                    v = fmaxf(v, 0.f);
                } else if (ACT == ACT_SIGMOID) {
                    v = 1.f/(1.f + expf(-v));
                } else { // RESBN: relu -> *gamma/sqrt(1+eps)+beta -> +R
                    v = fmaxf(v, 0.f);
                    v = v*(gamma[c]*INVS) + beta[c];
                    v += R[(size_t)r*N + c];
                }
                C[(size_t)r*N + c] = v;
                if (C2) C2[(size_t)r*N + c] = v;
            }
        }
    }
}

// ---------------- split-K accumulating GEMM: C += A@W chunk ------------------
__global__ __launch_bounds__(256) void gemm_acc(
    const float* __restrict__ A, const float* __restrict__ W,
    float* __restrict__ C, int M, int N, int K, int kchunk)
{
    __shared__ float As[16][68];
    __shared__ float Bs[16][68];
    const int tx = threadIdx.x, ty = threadIdx.y;
    const int tid = ty*16 + tx;
    const int row0 = blockIdx.y*64, col0 = blockIdx.x*64;
    const int kbeg = blockIdx.z * kchunk, kend = kbeg + kchunk;
    float acc[4][4] = {};
    for (int k0 = kbeg; k0 < kend; k0 += 16) {
        #pragma unroll
        for (int t = tid; t < 1024; t += 256) {
            int r = t >> 4, c = t & 15;
            As[c][r] = A[(size_t)(row0+r)*K + k0 + c];
        }
        #pragma unroll
        for (int t = tid; t < 1024; t += 256) {
            int kr = t >> 6, c = t & 63;
            int gc = col0 + c;
            Bs[kr][c] = (gc < N) ? W[(size_t)(k0+kr)*N + gc] : 0.f;
        }
        __syncthreads();
        #pragma unroll
        for (int kk = 0; kk < 16; kk++) {
            float a[4], b[4];
            #pragma unroll
            for (int i = 0; i < 4; i++) a[i] = As[kk][ty*4+i];
            #pragma unroll
            for (int j = 0; j < 4; j++) b[j] = Bs[kk][tx*4+j];
            #pragma unroll
            for (int i = 0; i < 4; i++)
                #pragma unroll
                for (int j = 0; j < 4; j++)
                    acc[i][j] += a[i]*b[j];
        }
        __syncthreads();
    }
    #pragma unroll
    for (int i = 0; i < 4; i++) {
        int r = row0 + ty*4 + i;
        #pragma unroll
        for (int j = 0; j < 4; j++) {
            int c = col0 + tx*4 + j;
            if (c < N) atomicAdd(&C[(size_t)r*N + c], acc[i][j]);
        }
    }
}

// ---------------- epilogue for split-K results -------------------------------
template<int ACT>
__global__ __launch_bounds__(256) void epi_k(
    float* __restrict__ C, const float* __restrict__ bias,
    float* __restrict__ dst, int M, int N)
{
    int i = blockIdx.x*256 + threadIdx.x;
    if (i >= M*N) return;
    int c = i % N;
    float v = C[i] + bias[c];
    if (ACT == ACT_RELU) v = fmaxf(v, 0.f);
    else v = 1.f/(1.f + expf(-v));
    C[i] = v;
    if (dst) dst[i] = v;
}

__global__ __launch_bounds__(256) void zero_k(float* __restrict__ p, int n)
{
    int i = blockIdx.x*256 + threadIdx.x;
    if (i < n) p[i] = 0.f;
}

// ---------------- VQ table precompute ----------------------------------------
// dist(z,k) = ||e(z)-E_k||^2 - ||e||^2  (constant-per-element term dropped,
// as in all prior passing rounds) = C2[k] + sum_i a_i(z)*Hm2[k][i]
//   C2[k]  = Esq[k] - 2*dot(bt2, E_k)
//   Hm2[k][i] = -2*dot(Wt2[i,:], E_k)
__global__ __launch_bounds__(256) void esq2_k(
    const float* __restrict__ E, const float* __restrict__ bt2,
    const float* __restrict__ Wt2,
    float* __restrict__ C2, float* __restrict__ Hm2)
{
    int k = blockIdx.x*256 + threadIdx.x;
    if (k >= 512) return;
    const float4* Er = (const float4*)(E + (size_t)k*64);
    const float4* b4 = (const float4*)bt2;
    float esq = 0.f, g0 = 0.f;
    #pragma unroll
    for (int m = 0; m < 16; m++) {
        float4 w = Er[m]; float4 b = b4[m];
        esq += w.x*w.x + w.y*w.y + w.z*w.z + w.w*w.w;
        g0  += b.x*w.x + b.y*w.y + b.z*w.z + b.w*w.w;
    }
    C2[k] = esq - 2.f*g0;
    for (int i = 0; i < 32; i++) {
        const float4* Wr = (const float4*)(Wt2 + i*64);
        float h = 0.f;
        #pragma unroll
        for (int m = 0; m < 16; m++) {
            float4 w = Er[m]; float4 ww = Wr[m];
            h += w.x*ww.x + w.y*ww.y + w.z*ww.z + w.w*ww.w;
        }
        Hm2[(size_t)k*32 + i] = -2.f*h;
    }
}

// ---------------- VQ main: a(z) -> table argmin -> q/loss/counts -------------
// ROUND-7 DIAGNOSIS: the invariant ~2.2ms across all VQ variants was the
// qout WRITE pattern, not the compute. Per-thread row-scatter float2 stores
// put 8 dirty bytes in each 128-B line -> read-for-ownership fetch of ~every
// sector: FETCH ~= 67MB x16 = 1.07GB (matches r6/r7 counters), WRITE x4.
// The RFO storm saturates miss queues (VALUBusy 6-7%) and thrashes L2
// (which is why r6's scalar table loads missed). Fix: phases 1-2 are
// BITWISE IDENTICAL to round-6's passing vqh_k (global tables via s_load,
// VGPR=44, no spill); phase 3 writes qout WAVE-CONTIGUOUSLY: each wave owns
// a 16KB span, written in 512-B bursts (float2: o_q base is only 8B
// aligned), values re-gathered from the L2-resident 128KB codebook via
// rowbi[] in LDS. Full-sector coverage -> no RFO.
__global__ __launch_bounds__(256) void vqc_k(
    const float* __restrict__ zencf, const float* __restrict__ Wt1,
    const float* __restrict__ bt1, const float* __restrict__ bt2,
    const float* __restrict__ Wt2, const float* __restrict__ E,
    const float* __restrict__ C2, const float* __restrict__ Hm2,
    float* __restrict__ qout, float* __restrict__ sumsq,
    float* __restrict__ counts)
{
    __shared__ float aT[32][256];
    __shared__ int   rowbi[256];
    const int tid = threadIdx.x;
    const int gid = blockIdx.x*256 + tid;
    const float z = zencf[gid];

    float a[32];
    #pragma unroll
    for (int i = 0; i < 32; i++) {
        a[i] = fmaxf(z*Wt1[i] + bt1[i], 0.f);
        aT[i][tid] = a[i];
    }

    // ---- argmin_k  C2[k] + sum_i a_i * Hm2[k][i]  (first-min tie break) ----
    float best = 3.4e38f; int bi = 0;
    for (int k = 0; k < 512; k++) {
        const float* hp = Hm2 + k*32;   // wave-uniform -> s_load
        float s = C2[k];
        #pragma unroll
        for (int i = 0; i < 32; i++) s = fmaf(a[i], hp[i], s);
        if (s < best) { best = s; bi = k; }
    }
    atomicAdd(&counts[bi], 1.f);
    rowbi[tid] = bi;

    // ---- e recomputed for (q-e)^2; wave-reduce (no qout stores here) -------
    float ls = 0.f;
    const float4* Eq = (const float4*)(E + (size_t)bi*64);
    const float4* b4 = (const float4*)bt2;
    for (int m = 0; m < 16; m++) {
        float4 w = Eq[m];
        float4 e4 = b4[m];
        #pragma unroll 8
        for (int i = 0; i < 32; i++) {
            float ai = aT[i][tid];
            float4 wr = *(const float4*)(Wt2 + i*64 + 4*m);  // uniform -> s_load
            e4.x = fmaf(ai, wr.x, e4.x);
            e4.y = fmaf(ai, wr.y, e4.y);
            e4.z = fmaf(ai, wr.z, e4.z);
            e4.w = fmaf(ai, wr.w, e4.w);
        }
        float d;
        d = w.x - e4.x; ls += d*d;
        d = w.y - e4.y; ls += d*d;
        d = w.z - e4.z; ls += d*d;
        d = w.w - e4.w; ls += d*d;
    }
    #pragma unroll
    for (int off = 32; off > 0; off >>= 1)
        ls += __shfl_down(ls, off, 64);
    if ((tid & 63) == 0) atomicAdd(sumsq, ls);

    // ---- phase 3: wave-contiguous qout write (512-B bursts, no RFO) --------
    __syncthreads();
    const int wid  = tid >> 6;
    const int lane = tid & 63;
    // wave's span: rows [blockIdx*256 + wid*64, +64), 2048 float2 elements
    float2* qo2w = (float2*)qout + ((size_t)blockIdx.x*8192 + (size_t)wid*2048);
    const int rbase = wid*64;
    #pragma unroll 4
    for (int c = 0; c < 32; c++) {
        const int idx2 = c*64 + lane;            // float2 index in wave span
        const int r    = rbase + (idx2 >> 5);    // block-local row
        const int d2   = idx2 & 31;              // float2 index within row
        const int bir  = rowbi[r];
        float2 w2 = *((const float2*)(E + (size_t)bir*64) + d2);  // L2-hot
        qo2w[idx2] = w2;
    }
}

// ---------------- losses / perplexity ---------------------------------------
__global__ __launch_bounds__(512) void finalize_k(
    const float* __restrict__ sumsq, const float* __restrict__ counts,
    float* __restrict__ out)
{
    __shared__ float red[512];
    int tid = threadIdx.x;
    float p = counts[tid] * (1.f/262144.f);
    red[tid] = p * logf(p + 1e-10f);
    __syncthreads();
    for (int s = 256; s > 0; s >>= 1) { if (tid < s) red[tid] += red[tid+s]; __syncthreads(); }
    if (tid == 0) {
        out[0]       = 1.25f * sumsq[0] * (1.f/16777216.f); // vq_loss = (1+0.25)*mse
        out[2097153] = expf(-red[0]);                        // perplexity
    }
}

extern "C" void kernel_launch(void* const* d_in, const int* in_sizes, int n_in,
                              void* d_out, int out_size, void* d_ws, size_t ws_size,
                              hipStream_t stream)
{
    // Reference dtypes are float32 throughout -> all inputs/outputs are f32.
    const float* x    = (const float*)d_in[0];
    const float* We1  = (const float*)d_in[1];  const float* be1  = (const float*)d_in[2];
    const float* We2  = (const float*)d_in[3];  const float* be2  = (const float*)d_in[4];
    const float* Wre1 = (const float*)d_in[5];  const float* bre1 = (const float*)d_in[6];
    const float* Wre2 = (const float*)d_in[7];  const float* bre2 = (const float*)d_in[8];
    const float* ge   = (const float*)d_in[9];  const float* bebn = (const float*)d_in[10];
    const float* E    = (const float*)d_in[11];
    const float* Wt1  = (const float*)d_in[12]; const float* bt1  = (const float*)d_in[13];
    const float* Wt2  = (const float*)d_in[14]; const float* bt2  = (const float*)d_in[15];
    const float* Wc   = (const float*)d_in[16]; const float* bc   = (const float*)d_in[17];
    const float* Wp   = (const float*)d_in[18]; const float* bp   = (const float*)d_in[19];
    const float* Wrd1 = (const float*)d_in[20]; const float* brd1 = (const float*)d_in[21];
    const float* Wrd2 = (const float*)d_in[22]; const float* brd2 = (const float*)d_in[23];
    const float* gd   = (const float*)d_in[24]; const float* bdbn = (const float*)d_in[25];
    const float* Wd1  = (const float*)d_in[26]; const float* bd1  = (const float*)d_in[27];
    const float* Wd2  = (const float*)d_in[28]; const float* bd2  = (const float*)d_in[29];

    // f32 output, flat: vq_loss[1] | x_recon[2097152] | ppl[1] | q_st[16777216]
    //                  | cls[5120] | zenc[262144]
    float* out    = (float*)d_out;
    float* o_xr   = out + 1;
    float* o_q    = out + 2097154;
    float* o_cls  = out + 18874370;
    float* o_zenc = out + 18879490;

    // ws (floats): small zeroed buffers first; total ~8.5 MB.
    float* ws    = (float*)d_ws;
    float* sumsq = ws + 0;        // 1      [zeroed]
    float* cnts  = ws + 16;       // 512    [zeroed]
    float* t1    = ws + 528;      // 8192   [zeroed]
    float* t2    = ws + 8720;     // 8192   [zeroed]
    float* clsf  = ws + 16912;    // 5120   [zeroed]
    float* z0    = ws + 22032;    // 262144 [zeroed]
    float* dp0   = ws + 284176;   // 262144 [zeroed]
    float* zencf = ws + 546320;   // 262144
    float* dd    = ws + 808464;   // 262144
    float* hbuf  = ws + 1070608;  // 1048576 (dead between We2-gemm and d2)
    float* d2    = ws + 1070608;
    // VQ tables alias hbuf: written by esq2_k AFTER the We2 gemm consumed
    // hbuf, read by vqc_k, dead before the Wd1 gemm overwrites d2.
    float* c2t   = ws + 1070608;  // 512
    float* hm2t  = ws + 1071120;  // 16384

    dim3 blk(16, 16);

    zero_k<<<dim3(2135), dim3(256), 0, stream>>>(ws, 546320);

    // ---- encoder ----
    gemm_fused<ACT_RELU><<<dim3(32, 8), blk, 0, stream>>>(
        x, We1, be1, hbuf, nullptr, nullptr, nullptr, nullptr, 512, 2048, 4096);
    gemm_acc<<<dim3(8, 8, 4), blk, 0, stream>>>(hbuf, We2, z0, 512, 512, 2048, 512);
    epi_k<ACT_RELU><<<dim3(1024), dim3(256), 0, stream>>>(z0, be2, nullptr, 512, 512);
    gemm_acc<<<dim3(1, 8, 32), blk, 0, stream>>>(z0, Wre1, t1, 512, 16, 512, 16);
    epi_k<ACT_RELU><<<dim3(32), dim3(256), 0, stream>>>(t1, bre1, nullptr, 512, 16);
    gemm_fused<ACT_RESBN><<<dim3(8, 8), blk, 0, stream>>>(
        t1, Wre2, bre2, zencf, o_zenc, z0, ge, bebn, 512, 512, 16);

    // ---- vector quantizer ----
    esq2_k<<<dim3(2), dim3(256), 0, stream>>>(E, bt2, Wt2, c2t, hm2t);
    vqc_k<<<dim3(1024), dim3(256), 0, stream>>>(zencf, Wt1, bt1, bt2, Wt2, E,
                                                c2t, hm2t, o_q, sumsq, cnts);
    finalize_k<<<dim3(1), dim3(512), 0, stream>>>(sumsq, cnts, out);

    // ---- classifier head ----
    gemm_acc<<<dim3(1, 8, 32), blk, 0, stream>>>(o_q, Wc, clsf, 512, 10, 32768, 1024);
    epi_k<ACT_SIGMOID><<<dim3(20), dim3(256), 0, stream>>>(clsf, bc, o_cls, 512, 10);

    // ---- decoder ----
    gemm_acc<<<dim3(8, 8, 8), blk, 0, stream>>>(o_q, Wp, dp0, 512, 512, 32768, 4096);
    epi_k<ACT_RELU><<<dim3(1024), dim3(256), 0, stream>>>(dp0, bp, nullptr, 512, 512);
    gemm_acc<<<dim3(1, 8, 32), blk, 0, stream>>>(dp0, Wrd1, t2, 512, 16, 512, 16);
    epi_k<ACT_RELU><<<dim3(32), dim3(256), 0, stream>>>(t2, brd1, nullptr, 512, 16);
    gemm_fused<ACT_RESBN><<<dim3(8, 8), blk, 0, stream>>>(
        t2, Wrd2, brd2, dd, nullptr, dp0, gd, bdbn, 512, 512, 16);
    gemm_fused<ACT_RELU><<<dim3(32, 8), blk, 0, stream>>>(
        dd, Wd1, bd1, d2, nullptr, nullptr, nullptr, nullptr, 512, 2048, 512);
    gemm_fused<ACT_RELU><<<dim3(64, 8), blk, 0, stream>>>(
        d2, Wd2, bd2, o_xr, nullptr, nullptr, nullptr, nullptr, 512, 4096, 2048);
}

// Round 9
// 2838.348 us; speedup vs baseline: 1.6824x; 1.6824x over previous
//
#include <hip/hip_runtime.h>

typedef unsigned int uint;

enum { ACT_RELU=0, ACT_SIGMOID=1, ACT_RESBN=2 };

// ---------------- fused GEMM (f32): C = act(A @ W + bias) [+BN/residual] -----
// A:[M,K] row-major, W:[K,N] row-major. Optional second store C2 (same values).
// tile 64x64, BK=16, 256 threads, 4x4 acc/thread. M%64==0, K%16==0.
template<int ACT>
__global__ __launch_bounds__(256) void gemm_fused(
    const float* __restrict__ A, const float* __restrict__ W,
    const float* __restrict__ bias, float* __restrict__ C,
    float* __restrict__ C2, const float* __restrict__ R,
    const float* __restrict__ gamma, const float* __restrict__ beta,
    int M, int N, int K)
{
    __shared__ float As[16][68];
    __shared__ float Bs[16][68];
    const int tx = threadIdx.x, ty = threadIdx.y;
    const int tid = ty*16 + tx;
    const int row0 = blockIdx.y*64, col0 = blockIdx.x*64;
    float acc[4][4] = {};
    for (int k0 = 0; k0 < K; k0 += 16) {
        #pragma unroll
        for (int t = tid; t < 1024; t += 256) {
            int r = t >> 4, c = t & 15;
            As[c][r] = A[(size_t)(row0+r)*K + k0 + c];
        }
        #pragma unroll
        for (int t = tid; t < 1024; t += 256) {
            int kr = t >> 6, c = t & 63;
            int gc = col0 + c;
            Bs[kr][c] = (gc < N) ? W[(size_t)(k0+kr)*N + gc] : 0.f;
        }
        __syncthreads();
        #pragma unroll
        for (int kk = 0; kk < 16; kk++) {
            float a[4], b[4];
            #pragma unroll
            for (int i = 0; i < 4; i++) a[i] = As[kk][ty*4+i];
            #pragma unroll
            for (int j = 0; j < 4; j++) b[j] = Bs[kk][tx*4+j];
            #pragma unroll
            for (int i = 0; i < 4; i++)
                #pragma unroll
                for (int j = 0; j < 4; j++)
                    acc[i][j] += a[i]*b[j];
        }
        __syncthreads();
    }
    const float INVS = 0.99999500003749968f; // 1/sqrt(1+1e-5)
    #pragma unroll
    for (int i = 0; i < 4; i++) {
        int r = row0 + ty*4 + i;
        #pragma unroll
        for (int j = 0; j < 4; j++) {
            int c = col0 + tx*4 + j;
            if (c < N) {
                float v = acc[i][j] + bias[c];
                if (ACT == ACT_RELU) {
                    v = fmaxf(v, 0.f);
                } else if (ACT == ACT_SIGMOID) {
                    v = 1.f/(1.f + expf(-v));
                } else { // RESBN: relu -> *gamma/sqrt(1+eps)+beta -> +R
                    v = fmaxf(v, 0.f);
                    v = v*(gamma[c]*INVS) + beta[c];
                    v += R[(size_t)r*N + c];
                }
                C[(size_t)r*N + c] = v;
                if (C2) C2[(size_t)r*N + c] = v;
            }
        }
    }
}

// ---------------- split-K accumulating GEMM: C += A@W chunk ------------------
__global__ __launch_bounds__(256) void gemm_acc(
    const float* __restrict__ A, const float* __restrict__ W,
    float* __restrict__ C, int M, int N, int K, int kchunk)
{
    __shared__ float As[16][68];
    __shared__ float Bs[16][68];
    const int tx = threadIdx.x, ty = threadIdx.y;
    const int tid = ty*16 + tx;
    const int row0 = blockIdx.y*64, col0 = blockIdx.x*64;
    const int kbeg = blockIdx.z * kchunk, kend = kbeg + kchunk;
    float acc[4][4] = {};
    for (int k0 = kbeg; k0 < kend; k0 += 16) {
        #pragma unroll
        for (int t = tid; t < 1024; t += 256) {
            int r = t >> 4, c = t & 15;
            As[c][r] = A[(size_t)(row0+r)*K + k0 + c];
        }
        #pragma unroll
        for (int t = tid; t < 1024; t += 256) {
            int kr = t >> 6, c = t & 63;
            int gc = col0 + c;
            Bs[kr][c] = (gc < N) ? W[(size_t)(k0+kr)*N + gc] : 0.f;
        }
        __syncthreads();
        #pragma unroll
        for (int kk = 0; kk < 16; kk++) {
            float a[4], b[4];
            #pragma unroll
            for (int i = 0; i < 4; i++) a[i] = As[kk][ty*4+i];
            #pragma unroll
            for (int j = 0; j < 4; j++) b[j] = Bs[kk][tx*4+j];
            #pragma unroll
            for (int i = 0; i < 4; i++)
                #pragma unroll
                for (int j = 0; j < 4; j++)
                    acc[i][j] += a[i]*b[j];
        }
        __syncthreads();
    }
    #pragma unroll
    for (int i = 0; i < 4; i++) {
        int r = row0 + ty*4 + i;
        #pragma unroll
        for (int j = 0; j < 4; j++) {
            int c = col0 + tx*4 + j;
            if (c < N) atomicAdd(&C[(size_t)r*N + c], acc[i][j]);
        }
    }
}

// ---------------- epilogue for split-K results -------------------------------
template<int ACT>
__global__ __launch_bounds__(256) void epi_k(
    float* __restrict__ C, const float* __restrict__ bias,
    float* __restrict__ dst, int M, int N)
{
    int i = blockIdx.x*256 + threadIdx.x;
    if (i >= M*N) return;
    int c = i % N;
    float v = C[i] + bias[c];
    if (ACT == ACT_RELU) v = fmaxf(v, 0.f);
    else v = 1.f/(1.f + expf(-v));
    C[i] = v;
    if (dst) dst[i] = v;
}

__global__ __launch_bounds__(256) void zero_k(float* __restrict__ p, int n)
{
    int i = blockIdx.x*256 + threadIdx.x;
    if (i < n) p[i] = 0.f;
}

// ---------------- VQ table precompute ----------------------------------------
// dist(z,k) = ||e(z)-E_k||^2 - ||e||^2  (constant-per-element term dropped,
// as in all prior passing rounds) = C2[k] + sum_i a_i(z)*Hm2[k][i]
//   C2[k]  = Esq[k] - 2*dot(bt2, E_k)
//   Hm2[k][i] = -2*dot(Wt2[i,:], E_k)
__global__ __launch_bounds__(256) void esq2_k(
    const float* __restrict__ E, const float* __restrict__ bt2,
    const float* __restrict__ Wt2,
    float* __restrict__ C2, float* __restrict__ Hm2)
{
    int k = blockIdx.x*256 + threadIdx.x;
    if (k >= 512) return;
    const float4* Er = (const float4*)(E + (size_t)k*64);
    const float4* b4 = (const float4*)bt2;
    float esq = 0.f, g0 = 0.f;
    #pragma unroll
    for (int m = 0; m < 16; m++) {
        float4 w = Er[m]; float4 b = b4[m];
        esq += w.x*w.x + w.y*w.y + w.z*w.z + w.w*w.w;
        g0  += b.x*w.x + b.y*w.y + b.z*w.z + b.w*w.w;
    }
    C2[k] = esq - 2.f*g0;
    for (int i = 0; i < 32; i++) {
        const float4* Wr = (const float4*)(Wt2 + i*64);
        float h = 0.f;
        #pragma unroll
        for (int m = 0; m < 16; m++) {
            float4 w = Er[m]; float4 ww = Wr[m];
            h += w.x*ww.x + w.y*ww.y + w.z*ww.z + w.w*ww.w;
        }
        Hm2[(size_t)k*32 + i] = -2.f*h;
    }
}

// ---------------- VQ main: a(z) -> table argmin -> q/loss/hist ---------------
// ROUND-8 DIAGNOSIS: with writes fixed (74MB) and FETCH ~1MB (units: KB!),
// ALL pipes are idle yet every structure since r0 lands at 2.07-2.29 ms.
// The invariant across all eight structures: 262144 divergent global
// atomicAdd(&counts[bi]) into a 2KB region -- one interleave granule ->
// one fabric atomic point serializes the whole chip (~8ns x 262144 = 2.1ms,
// matching the floor and its indifference to occupancy). FIX: zero global
// atomics. Per-block LDS int histogram -> plain coalesced 2KB store into
// hist[block][512]; sumsq via shfl wave-reduce -> block partial -> plain
// store; finalize_k does the deterministic global reduction. Counts are
// integer-valued f32 (<2^24): bitwise-identical counts and perplexity.
// Phases 1-3 compute identical to r8 (which passed).
__global__ __launch_bounds__(256) void vqc_k(
    const float* __restrict__ zencf, const float* __restrict__ Wt1,
    const float* __restrict__ bt1, const float* __restrict__ bt2,
    const float* __restrict__ Wt2, const float* __restrict__ E,
    const float* __restrict__ C2, const float* __restrict__ Hm2,
    float* __restrict__ qout, float* __restrict__ hist,
    float* __restrict__ sspart)
{
    __shared__ float aT[32][256];
    __shared__ int   rowbi[256];
    __shared__ int   hcnt[512];
    __shared__ float red4[4];
    const int tid = threadIdx.x;
    const int gid = blockIdx.x*256 + tid;
    const float z = zencf[gid];

    hcnt[tid] = 0; hcnt[tid + 256] = 0;

    float a[32];
    #pragma unroll
    for (int i = 0; i < 32; i++) {
        a[i] = fmaxf(z*Wt1[i] + bt1[i], 0.f);
        aT[i][tid] = a[i];
    }
    __syncthreads();   // hcnt zeroed before any histogram add

    // ---- argmin_k  C2[k] + sum_i a_i * Hm2[k][i]  (first-min tie break) ----
    float best = 3.4e38f; int bi = 0;
    for (int k = 0; k < 512; k++) {
        const float* hp = Hm2 + k*32;   // wave-uniform -> s_load
        float s = C2[k];
        #pragma unroll
        for (int i = 0; i < 32; i++) s = fmaf(a[i], hp[i], s);
        if (s < best) { best = s; bi = k; }
    }
    atomicAdd(&hcnt[bi], 1);            // LDS atomic, cheap
    rowbi[tid] = bi;

    // ---- e recomputed for (q-e)^2; wave-reduce to block partial ------------
    float ls = 0.f;
    const float4* Eq = (const float4*)(E + (size_t)bi*64);
    const float4* b4 = (const float4*)bt2;
    for (int m = 0; m < 16; m++) {
        float4 w = Eq[m];
        float4 e4 = b4[m];
        #pragma unroll 8
        for (int i = 0; i < 32; i++) {
            float ai = aT[i][tid];
            float4 wr = *(const float4*)(Wt2 + i*64 + 4*m);  // uniform -> s_load
            e4.x = fmaf(ai, wr.x, e4.x);
            e4.y = fmaf(ai, wr.y, e4.y);
            e4.z = fmaf(ai, wr.z, e4.z);
            e4.w = fmaf(ai, wr.w, e4.w);
        }
        float d;
        d = w.x - e4.x; ls += d*d;
        d = w.y - e4.y; ls += d*d;
        d = w.z - e4.z; ls += d*d;
        d = w.w - e4.w; ls += d*d;
    }
    #pragma unroll
    for (int off = 32; off > 0; off >>= 1)
        ls += __shfl_down(ls, off, 64);
    if ((tid & 63) == 0) red4[tid >> 6] = ls;

    __syncthreads();   // rowbi, hcnt, red4 all complete

    if (tid == 0)
        sspart[blockIdx.x] = ((red4[0] + red4[1]) + red4[2]) + red4[3];
    // per-block histogram: plain coalesced stores (no global atomics)
    hist[(size_t)blockIdx.x*512 + tid]       = (float)hcnt[tid];
    hist[(size_t)blockIdx.x*512 + 256 + tid] = (float)hcnt[tid + 256];

    // ---- phase 3: wave-contiguous qout write (512-B bursts, no RFO) --------
    const int wid  = tid >> 6;
    const int lane = tid & 63;
    // wave's span: rows [blockIdx*256 + wid*64, +64), 2048 float2 elements
    float2* qo2w = (float2*)qout + ((size_t)blockIdx.x*8192 + (size_t)wid*2048);
    const int rbase = wid*64;
    #pragma unroll 4
    for (int c = 0; c < 32; c++) {
        const int idx2 = c*64 + lane;            // float2 index in wave span
        const int r    = rbase + (idx2 >> 5);    // block-local row
        const int d2   = idx2 & 31;              // float2 index within row
        const int bir  = rowbi[r];
        float2 w2 = *((const float2*)(E + (size_t)bir*64) + d2);  // L2-hot
        qo2w[idx2] = w2;
    }
}

// ---------------- losses / perplexity (deterministic reductions) -------------
__global__ __launch_bounds__(512) void finalize_k(
    const float* __restrict__ hist, const float* __restrict__ sspart,
    float* __restrict__ out)
{
    __shared__ float red[512];
    int tid = threadIdx.x;
    // counts[tid] = sum over 1024 block histograms (coalesced across tid)
    float c = 0.f;
    for (int b = 0; b < 1024; b++) c += hist[(size_t)b*512 + tid];
    // sumsq = sum of 1024 block partials
    red[tid] = sspart[tid] + sspart[tid + 512];
    __syncthreads();
    for (int s = 256; s > 0; s >>= 1) { if (tid < s) red[tid] += red[tid+s]; __syncthreads(); }
    float ss = red[0];
    __syncthreads();
    float p = c * (1.f/262144.f);
    red[tid] = p * logf(p + 1e-10f);
    __syncthreads();
    for (int s = 256; s > 0; s >>= 1) { if (tid < s) red[tid] += red[tid+s]; __syncthreads(); }
    if (tid == 0) {
        out[0]       = 1.25f * ss * (1.f/16777216.f); // vq_loss = (1+0.25)*mse
        out[2097153] = expf(-red[0]);                  // perplexity
    }
}

extern "C" void kernel_launch(void* const* d_in, const int* in_sizes, int n_in,
                              void* d_out, int out_size, void* d_ws, size_t ws_size,
                              hipStream_t stream)
{
    // Reference dtypes are float32 throughout -> all inputs/outputs are f32.
    const float* x    = (const float*)d_in[0];
    const float* We1  = (const float*)d_in[1];  const float* be1  = (const float*)d_in[2];
    const float* We2  = (const float*)d_in[3];  const float* be2  = (const float*)d_in[4];
    const float* Wre1 = (const float*)d_in[5];  const float* bre1 = (const float*)d_in[6];
    const float* Wre2 = (const float*)d_in[7];  const float* bre2 = (const float*)d_in[8];
    const float* ge   = (const float*)d_in[9];  const float* bebn = (const float*)d_in[10];
    const float* E    = (const float*)d_in[11];
    const float* Wt1  = (const float*)d_in[12]; const float* bt1  = (const float*)d_in[13];
    const float* Wt2  = (const float*)d_in[14]; const float* bt2  = (const float*)d_in[15];
    const float* Wc   = (const float*)d_in[16]; const float* bc   = (const float*)d_in[17];
    const float* Wp   = (const float*)d_in[18]; const float* bp   = (const float*)d_in[19];
    const float* Wrd1 = (const float*)d_in[20]; const float* brd1 = (const float*)d_in[21];
    const float* Wrd2 = (const float*)d_in[22]; const float* brd2 = (const float*)d_in[23];
    const float* gd   = (const float*)d_in[24]; const float* bdbn = (const float*)d_in[25];
    const float* Wd1  = (const float*)d_in[26]; const float* bd1  = (const float*)d_in[27];
    const float* Wd2  = (const float*)d_in[28]; const float* bd2  = (const float*)d_in[29];

    // f32 output, flat: vq_loss[1] | x_recon[2097152] | ppl[1] | q_st[16777216]
    //                  | cls[5120] | zenc[262144]
    float* out    = (float*)d_out;
    float* o_xr   = out + 1;
    float* o_q    = out + 2097154;
    float* o_cls  = out + 18874370;
    float* o_zenc = out + 18879490;

    // ws (floats): small zeroed buffers first; total ~8.5 MB.
    float* ws    = (float*)d_ws;
    float* sumsq = ws + 0;        // 1      [zeroed] (unused now)
    float* cnts  = ws + 16;       // 512    [zeroed] (unused now)
    float* t1    = ws + 528;      // 8192   [zeroed]
    float* t2    = ws + 8720;     // 8192   [zeroed]
    float* clsf  = ws + 16912;    // 5120   [zeroed]
    float* z0    = ws + 22032;    // 262144 [zeroed]
    float* dp0   = ws + 284176;   // 262144 [zeroed]
    float* zencf = ws + 546320;   // 262144
    float* dd    = ws + 808464;   // 262144
    float* hbuf  = ws + 1070608;  // 1048576 (dead between We2-gemm and d2)
    float* d2    = ws + 1070608;
    // VQ tables + hist alias hbuf: written AFTER the We2 gemm consumed hbuf,
    // read by vqc_k/finalize_k, dead before the Wd1 gemm overwrites d2.
    float* c2t   = ws + 1070608;  // 512
    float* hm2t  = ws + 1071120;  // 16384
    float* hist  = ws + 1087504;  // 524288 (1024 blocks x 512 bins)
    float* sspart= ws + 1611792;  // 1024
    // end 1612816 < 1070608+1048576 = 2119184  (fits in hbuf span)

    dim3 blk(16, 16);

    zero_k<<<dim3(2135), dim3(256), 0, stream>>>(ws, 546320);

    // ---- encoder ----
    gemm_fused<ACT_RELU><<<dim3(32, 8), blk, 0, stream>>>(
        x, We1, be1, hbuf, nullptr, nullptr, nullptr, nullptr, 512, 2048, 4096);
    gemm_acc<<<dim3(8, 8, 4), blk, 0, stream>>>(hbuf, We2, z0, 512, 512, 2048, 512);
    epi_k<ACT_RELU><<<dim3(1024), dim3(256), 0, stream>>>(z0, be2, nullptr, 512, 512);
    gemm_acc<<<dim3(1, 8, 32), blk, 0, stream>>>(z0, Wre1, t1, 512, 16, 512, 16);
    epi_k<ACT_RELU><<<dim3(32), dim3(256), 0, stream>>>(t1, bre1, nullptr, 512, 16);
    gemm_fused<ACT_RESBN><<<dim3(8, 8), blk, 0, stream>>>(
        t1, Wre2, bre2, zencf, o_zenc, z0, ge, bebn, 512, 512, 16);

    // ---- vector quantizer ----
    esq2_k<<<dim3(2), dim3(256), 0, stream>>>(E, bt2, Wt2, c2t, hm2t);
    vqc_k<<<dim3(1024), dim3(256), 0, stream>>>(zencf, Wt1, bt1, bt2, Wt2, E,
                                                c2t, hm2t, o_q, hist, sspart);
    finalize_k<<<dim3(1), dim3(512), 0, stream>>>(hist, sspart, out);

    // ---- classifier head ----
    gemm_acc<<<dim3(1, 8, 32), blk, 0, stream>>>(o_q, Wc, clsf, 512, 10, 32768, 1024);
    epi_k<ACT_SIGMOID><<<dim3(20), dim3(256), 0, stream>>>(clsf, bc, o_cls, 512, 10);

    // ---- decoder ----
    gemm_acc<<<dim3(8, 8, 8), blk, 0, stream>>>(o_q, Wp, dp0, 512, 512, 32768, 4096);
    epi_k<ACT_RELU><<<dim3(1024), dim3(256), 0, stream>>>(dp0, bp, nullptr, 512, 512);
    gemm_acc<<<dim3(1, 8, 32), blk, 0, stream>>>(dp0, Wrd1, t2, 512, 16, 512, 16);
    epi_k<ACT_RELU><<<dim3(32), dim3(256), 0, stream>>>(t2, brd1, nullptr, 512, 16);
    gemm_fused<ACT_RESBN><<<dim3(8, 8), blk, 0, stream>>>(
        t2, Wrd2, brd2, dd, nullptr, dp0, gd, bdbn, 512, 512, 16);
    gemm_fused<ACT_RELU><<<dim3(32, 8), blk, 0, stream>>>(
        dd, Wd1, bd1, d2, nullptr, nullptr, nullptr, nullptr, 512, 2048, 512);
    gemm_fused<ACT_RELU><<<dim3(64, 8), blk, 0, stream>>>(
        d2, Wd2, bd2, o_xr, nullptr, nullptr, nullptr, nullptr, 512, 4096, 2048);
}

// Round 11
// 2386.878 us; speedup vs baseline: 2.0006x; 1.1891x over previous
//
#include <hip/hip_runtime.h>

typedef unsigned int uint;

enum { ACT_RELU=0, ACT_SIGMOID=1, ACT_RESBN=2 };

// ---------------- fused GEMM (f32): C = act(A @ W + bias) [+BN/residual] -----
// Used only for the two tiny 512x512x16 residual-BN gemms now.
template<int ACT>
__global__ __launch_bounds__(256) void gemm_fused(
    const float* __restrict__ A, const float* __restrict__ W,
    const float* __restrict__ bias, float* __restrict__ C,
    float* __restrict__ C2, const float* __restrict__ R,
    const float* __restrict__ gamma, const float* __restrict__ beta,
    int M, int N, int K)
{
    __shared__ float As[16][68];
    __shared__ float Bs[16][68];
    const int tx = threadIdx.x, ty = threadIdx.y;
    const int tid = ty*16 + tx;
    const int row0 = blockIdx.y*64, col0 = blockIdx.x*64;
    float acc[4][4] = {};
    for (int k0 = 0; k0 < K; k0 += 16) {
        #pragma unroll
        for (int t = tid; t < 1024; t += 256) {
            int r = t >> 4, c = t & 15;
            As[c][r] = A[(size_t)(row0+r)*K + k0 + c];
        }
        #pragma unroll
        for (int t = tid; t < 1024; t += 256) {
            int kr = t >> 6, c = t & 63;
            int gc = col0 + c;
            Bs[kr][c] = (gc < N) ? W[(size_t)(k0+kr)*N + gc] : 0.f;
        }
        __syncthreads();
        #pragma unroll
        for (int kk = 0; kk < 16; kk++) {
            float a[4], b[4];
            #pragma unroll
            for (int i = 0; i < 4; i++) a[i] = As[kk][ty*4+i];
            #pragma unroll
            for (int j = 0; j < 4; j++) b[j] = Bs[kk][tx*4+j];
            #pragma unroll
            for (int i = 0; i < 4; i++)
                #pragma unroll
                for (int j = 0; j < 4; j++)
                    acc[i][j] += a[i]*b[j];
        }
        __syncthreads();
    }
    const float INVS = 0.99999500003749968f; // 1/sqrt(1+1e-5)
    #pragma unroll
    for (int i = 0; i < 4; i++) {
        int r = row0 + ty*4 + i;
        #pragma unroll
        for (int j = 0; j < 4; j++) {
            int c = col0 + tx*4 + j;
            if (c < N) {
                float v = acc[i][j] + bias[c];
                if (ACT == ACT_RELU) {
                    v = fmaxf(v, 0.f);
                } else if (ACT == ACT_SIGMOID) {
                    v = 1.f/(1.f + expf(-v));
                } else { // RESBN: relu -> *gamma/sqrt(1+eps)+beta -> +R
                    v = fmaxf(v, 0.f);
                    v = v*(gamma[c]*INVS) + beta[c];
                    v += R[(size_t)r*N + c];
                }
                C[(size_t)r*N + c] = v;
                if (C2) C2[(size_t)r*N + c] = v;
            }
        }
    }
}

// ---------------- split-K accumulating GEMM (small-N path: Wre/Wrd/Wc) ------
__global__ __launch_bounds__(256) void gemm_acc(
    const float* __restrict__ A, const float* __restrict__ W,
    float* __restrict__ C, int M, int N, int K, int kchunk)
{
    __shared__ float As[16][68];
    __shared__ float Bs[16][68];
    const int tx = threadIdx.x, ty = threadIdx.y;
    const int tid = ty*16 + tx;
    const int row0 = blockIdx.y*64, col0 = blockIdx.x*64;
    const int kbeg = blockIdx.z * kchunk, kend = kbeg + kchunk;
    float acc[4][4] = {};
    for (int k0 = kbeg; k0 < kend; k0 += 16) {
        #pragma unroll
        for (int t = tid; t < 1024; t += 256) {
            int r = t >> 4, c = t & 15;
            As[c][r] = A[(size_t)(row0+r)*K + k0 + c];
        }
        #pragma unroll
        for (int t = tid; t < 1024; t += 256) {
            int kr = t >> 6, c = t & 63;
            int gc = col0 + c;
            Bs[kr][c] = (gc < N) ? W[(size_t)(k0+kr)*N + gc] : 0.f;
        }
        __syncthreads();
        #pragma unroll
        for (int kk = 0; kk < 16; kk++) {
            float a[4], b[4];
            #pragma unroll
            for (int i = 0; i < 4; i++) a[i] = As[kk][ty*4+i];
            #pragma unroll
            for (int j = 0; j < 4; j++) b[j] = Bs[kk][tx*4+j];
            #pragma unroll
            for (int i = 0; i < 4; i++)
                #pragma unroll
                for (int j = 0; j < 4; j++)
                    acc[i][j] += a[i]*b[j];
        }
        __syncthreads();
    }
    #pragma unroll
    for (int i = 0; i < 4; i++) {
        int r = row0 + ty*4 + i;
        #pragma unroll
        for (int j = 0; j < 4; j++) {
            int c = col0 + tx*4 + j;
            if (c < N) atomicAdd(&C[(size_t)r*N + c], acc[i][j]);
        }
    }
}

// 8B-aligned float4 load (for buffers whose base is only 8B-aligned, e.g. o_q)
__device__ inline float4 ld4_a8(const float* p) {
    float2 lo = *(const float2*)p;
    float2 hi = *(const float2*)(p + 2);
    return make_float4(lo.x, lo.y, hi.x, hi.y);
}

// ---------------- big-tile split-K GEMM: C += A@W chunk ----------------------
// 128x128 tile, BK=16, 256 threads, 8x8 acc/thread (64 FMA : 4 ds_read_b128
// per kk -> FMA-bound). Register-prefetch pipeline: next tile's loads issue
// right after the barrier so HBM latency hides under the compute phase.
// A16: A base is 16B-aligned (o_q is only 8B-aligned -> A16=false uses
// float2-pair loads; round-10 lesson: misaligned dwordx4 on o_q faulted).
// waves_per_eu(2,4): allocator targets <=4 waves/EU (128-VGPR budget, fits
// acc[8][8]+staging ~112) instead of spilling acc chasing 8 waves (r1-3
// lesson). Grid is 512 blocks = 2 waves/SIMD anyway.
// Requires M%128==0, N%128==0, kchunk%16==0 (all call sites satisfy).
template<bool A16>
__global__ __launch_bounds__(256)
__attribute__((amdgpu_waves_per_eu(2, 4)))
void gemm_big(
    const float* __restrict__ A, const float* __restrict__ W,
    float* __restrict__ C, int M, int N, int K, int kchunk)
{
    __shared__ float As[16][132];
    __shared__ float Bs[16][132];
    const int tid = threadIdx.x;
    const int tx = tid & 15, ty = tid >> 4;
    const int row0 = blockIdx.y*128, col0 = blockIdx.x*128;
    const size_t kbeg = (size_t)blockIdx.z * kchunk;

    const int ar0 = tid >> 2;            // A rows 0..63
    const int ac0 = (tid & 3) * 4;       // A k-offset {0,4,8,12}
    const int ar1 = ar0 + 64;            // A rows 64..127
    const int bk0 = tid >> 5;            // B k-rows 0..7
    const int bc0 = (tid & 31) * 4;      // B n-offset
    const int bk1 = bk0 + 8;             // B k-rows 8..15

    const float* Ap0 = A + (size_t)(row0 + ar0)*K + kbeg + ac0;
    const float* Ap1 = A + (size_t)(row0 + ar1)*K + kbeg + ac0;
    const float* Bp0 = W + (kbeg + bk0)*(size_t)N + col0 + bc0;
    const float* Bp1 = W + (kbeg + bk1)*(size_t)N + col0 + bc0;

    float4 pa0 = A16 ? *(const float4*)Ap0 : ld4_a8(Ap0);
    float4 pa1 = A16 ? *(const float4*)Ap1 : ld4_a8(Ap1);
    float4 pb0 = *(const float4*)Bp0;
    float4 pb1 = *(const float4*)Bp1;

    float acc[8][8] = {};

    for (int k0 = 0; k0 < kchunk; k0 += 16) {
        // store staged regs -> LDS (A transposed to [k][m])
        As[ac0+0][ar0] = pa0.x; As[ac0+1][ar0] = pa0.y;
        As[ac0+2][ar0] = pa0.z; As[ac0+3][ar0] = pa0.w;
        As[ac0+0][ar1] = pa1.x; As[ac0+1][ar1] = pa1.y;
        As[ac0+2][ar1] = pa1.z; As[ac0+3][ar1] = pa1.w;
        *(float4*)&Bs[bk0][bc0] = pb0;
        *(float4*)&Bs[bk1][bc0] = pb1;
        __syncthreads();
        if (k0 + 16 < kchunk) {      // prefetch next tile; waits land next iter
            pa0 = A16 ? *(const float4*)(Ap0 + k0 + 16) : ld4_a8(Ap0 + k0 + 16);
            pa1 = A16 ? *(const float4*)(Ap1 + k0 + 16) : ld4_a8(Ap1 + k0 + 16);
            pb0 = *(const float4*)(Bp0 + (size_t)(k0+16)*N);
            pb1 = *(const float4*)(Bp1 + (size_t)(k0+16)*N);
        }
        #pragma unroll
        for (int kk = 0; kk < 16; kk++) {
            float a[8], b[8];
            *(float4*)&a[0] = *(const float4*)&As[kk][ty*8];
            *(float4*)&a[4] = *(const float4*)&As[kk][ty*8+4];
            *(float4*)&b[0] = *(const float4*)&Bs[kk][tx*8];
            *(float4*)&b[4] = *(const float4*)&Bs[kk][tx*8+4];
            #pragma unroll
            for (int i = 0; i < 8; i++)
                #pragma unroll
                for (int j = 0; j < 8; j++)
                    acc[i][j] += a[i]*b[j];
        }
        __syncthreads();
    }

    #pragma unroll
    for (int i = 0; i < 8; i++) {
        float* crow = C + (size_t)(row0 + ty*8 + i)*N + col0 + tx*8;
        #pragma unroll
        for (int j = 0; j < 8; j++)
            atomicAdd(crow + j, acc[i][j]);
    }
}

// ---------------- epilogue for split-K results -------------------------------
template<int ACT>
__global__ __launch_bounds__(256) void epi_k(
    float* __restrict__ C, const float* __restrict__ bias,
    float* __restrict__ dst, int M, int N)
{
    int i = blockIdx.x*256 + threadIdx.x;
    if (i >= M*N) return;
    int c = i % N;
    float v = C[i] + bias[c];
    if (ACT == ACT_RELU) v = fmaxf(v, 0.f);
    else v = 1.f/(1.f + expf(-v));
    C[i] = v;
    if (dst) dst[i] = v;
}

__global__ __launch_bounds__(256) void zero_k(float* __restrict__ p, int n)
{
    int i = blockIdx.x*256 + threadIdx.x;
    if (i < n) p[i] = 0.f;
}

// ---------------- VQ table precompute ----------------------------------------
// dist(z,k) = C2[k] + sum_i a_i(z)*Hm2[k][i]
__global__ __launch_bounds__(256) void esq2_k(
    const float* __restrict__ E, const float* __restrict__ bt2,
    const float* __restrict__ Wt2,
    float* __restrict__ C2, float* __restrict__ Hm2)
{
    int k = blockIdx.x*256 + threadIdx.x;
    if (k >= 512) return;
    const float4* Er = (const float4*)(E + (size_t)k*64);
    const float4* b4 = (const float4*)bt2;
    float esq = 0.f, g0 = 0.f;
    #pragma unroll
    for (int m = 0; m < 16; m++) {
        float4 w = Er[m]; float4 b = b4[m];
        esq += w.x*w.x + w.y*w.y + w.z*w.z + w.w*w.w;
        g0  += b.x*w.x + b.y*w.y + b.z*w.z + b.w*w.w;
    }
    C2[k] = esq - 2.f*g0;
    for (int i = 0; i < 32; i++) {
        const float4* Wr = (const float4*)(Wt2 + i*64);
        float h = 0.f;
        #pragma unroll
        for (int m = 0; m < 16; m++) {
            float4 w = Er[m]; float4 ww = Wr[m];
            h += w.x*ww.x + w.y*ww.y + w.z*ww.z + w.w*ww.w;
        }
        Hm2[(size_t)k*32 + i] = -2.f*h;
    }
}

// ---------------- VQ main (r9 winner: zero global atomics) -------------------
__global__ __launch_bounds__(256) void vqc_k(
    const float* __restrict__ zencf, const float* __restrict__ Wt1,
    const float* __restrict__ bt1, const float* __restrict__ bt2,
    const float* __restrict__ Wt2, const float* __restrict__ E,
    const float* __restrict__ C2, const float* __restrict__ Hm2,
    float* __restrict__ qout, float* __restrict__ hist,
    float* __restrict__ sspart)
{
    __shared__ float aT[32][256];
    __shared__ int   rowbi[256];
    __shared__ int   hcnt[512];
    __shared__ float red4[4];
    const int tid = threadIdx.x;
    const int gid = blockIdx.x*256 + tid;
    const float z = zencf[gid];

    hcnt[tid] = 0; hcnt[tid + 256] = 0;

    float a[32];
    #pragma unroll
    for (int i = 0; i < 32; i++) {
        a[i] = fmaxf(z*Wt1[i] + bt1[i], 0.f);
        aT[i][tid] = a[i];
    }
    __syncthreads();   // hcnt zeroed before any histogram add

    float best = 3.4e38f; int bi = 0;
    for (int k = 0; k < 512; k++) {
        const float* hp = Hm2 + k*32;   // wave-uniform -> s_load
        float s = C2[k];
        #pragma unroll
        for (int i = 0; i < 32; i++) s = fmaf(a[i], hp[i], s);
        if (s < best) { best = s; bi = k; }
    }
    atomicAdd(&hcnt[bi], 1);            // LDS atomic, cheap
    rowbi[tid] = bi;

    float ls = 0.f;
    const float4* Eq = (const float4*)(E + (size_t)bi*64);
    const float4* b4 = (const float4*)bt2;
    for (int m = 0; m < 16; m++) {
        float4 w = Eq[m];
        float4 e4 = b4[m];
        #pragma unroll 8
        for (int i = 0; i < 32; i++) {
            float ai = aT[i][tid];
            float4 wr = *(const float4*)(Wt2 + i*64 + 4*m);  // uniform -> s_load
            e4.x = fmaf(ai, wr.x, e4.x);
            e4.y = fmaf(ai, wr.y, e4.y);
            e4.z = fmaf(ai, wr.z, e4.z);
            e4.w = fmaf(ai, wr.w, e4.w);
        }
        float d;
        d = w.x - e4.x; ls += d*d;
        d = w.y - e4.y; ls += d*d;
        d = w.z - e4.z; ls += d*d;
        d = w.w - e4.w; ls += d*d;
    }
    #pragma unroll
    for (int off = 32; off > 0; off >>= 1)
        ls += __shfl_down(ls, off, 64);
    if ((tid & 63) == 0) red4[tid >> 6] = ls;

    __syncthreads();   // rowbi, hcnt, red4 all complete

    if (tid == 0)
        sspart[blockIdx.x] = ((red4[0] + red4[1]) + red4[2]) + red4[3];
    hist[(size_t)blockIdx.x*512 + tid]       = (float)hcnt[tid];
    hist[(size_t)blockIdx.x*512 + 256 + tid] = (float)hcnt[tid + 256];

    // wave-contiguous qout write (512-B bursts, no RFO)
    const int wid  = tid >> 6;
    const int lane = tid & 63;
    float2* qo2w = (float2*)qout + ((size_t)blockIdx.x*8192 + (size_t)wid*2048);
    const int rbase = wid*64;
    #pragma unroll 4
    for (int c = 0; c < 32; c++) {
        const int idx2 = c*64 + lane;
        const int r    = rbase + (idx2 >> 5);
        const int d2   = idx2 & 31;
        const int bir  = rowbi[r];
        float2 w2 = *((const float2*)(E + (size_t)bir*64) + d2);
        qo2w[idx2] = w2;
    }
}

// ---------------- losses / perplexity (deterministic reductions) -------------
__global__ __launch_bounds__(512) void finalize_k(
    const float* __restrict__ hist, const float* __restrict__ sspart,
    float* __restrict__ out)
{
    __shared__ float red[512];
    int tid = threadIdx.x;
    float c = 0.f;
    for (int b = 0; b < 1024; b++) c += hist[(size_t)b*512 + tid];
    red[tid] = sspart[tid] + sspart[tid + 512];
    __syncthreads();
    for (int s = 256; s > 0; s >>= 1) { if (tid < s) red[tid] += red[tid+s]; __syncthreads(); }
    float ss = red[0];
    __syncthreads();
    float p = c * (1.f/262144.f);
    red[tid] = p * logf(p + 1e-10f);
    __syncthreads();
    for (int s = 256; s > 0; s >>= 1) { if (tid < s) red[tid] += red[tid+s]; __syncthreads(); }
    if (tid == 0) {
        out[0]       = 1.25f * ss * (1.f/16777216.f); // vq_loss = (1+0.25)*mse
        out[2097153] = expf(-red[0]);                  // perplexity
    }
}

extern "C" void kernel_launch(void* const* d_in, const int* in_sizes, int n_in,
                              void* d_out, int out_size, void* d_ws, size_t ws_size,
                              hipStream_t stream)
{
    const float* x    = (const float*)d_in[0];
    const float* We1  = (const float*)d_in[1];  const float* be1  = (const float*)d_in[2];
    const float* We2  = (const float*)d_in[3];  const float* be2  = (const float*)d_in[4];
    const float* Wre1 = (const float*)d_in[5];  const float* bre1 = (const float*)d_in[6];
    const float* Wre2 = (const float*)d_in[7];  const float* bre2 = (const float*)d_in[8];
    const float* ge   = (const float*)d_in[9];  const float* bebn = (const float*)d_in[10];
    const float* E    = (const float*)d_in[11];
    const float* Wt1  = (const float*)d_in[12]; const float* bt1  = (const float*)d_in[13];
    const float* Wt2  = (const float*)d_in[14]; const float* bt2  = (const float*)d_in[15];
    const float* Wc   = (const float*)d_in[16]; const float* bc   = (const float*)d_in[17];
    const float* Wp   = (const float*)d_in[18]; const float* bp   = (const float*)d_in[19];
    const float* Wrd1 = (const float*)d_in[20]; const float* brd1 = (const float*)d_in[21];
    const float* Wrd2 = (const float*)d_in[22]; const float* brd2 = (const float*)d_in[23];
    const float* gd   = (const float*)d_in[24]; const float* bdbn = (const float*)d_in[25];
    const float* Wd1  = (const float*)d_in[26]; const float* bd1  = (const float*)d_in[27];
    const float* Wd2  = (const float*)d_in[28]; const float* bd2  = (const float*)d_in[29];

    // f32 output, flat: vq_loss[1] | x_recon[2097152] | ppl[1] | q_st[16777216]
    //                  | cls[5120] | zenc[262144]
    float* out    = (float*)d_out;
    float* o_xr   = out + 1;
    float* o_q    = out + 2097154;
    float* o_cls  = out + 18874370;
    float* o_zenc = out + 18879490;

    // ws (floats)
    float* ws    = (float*)d_ws;
    float* t1    = ws + 528;      // 8192   [zeroed]
    float* t2    = ws + 8720;     // 8192   [zeroed]
    float* clsf  = ws + 16912;    // 5120   [zeroed]
    float* z0    = ws + 22032;    // 262144 [zeroed]
    float* dp0   = ws + 284176;   // 262144 [zeroed]
    float* zencf = ws + 546320;   // 262144
    float* dd    = ws + 808464;   // 262144
    float* hbuf  = ws + 1070608;  // 1048576 (We1 acc; dead after We2; reused)
    float* d2    = ws + 1070608;
    // VQ tables + hist alias hbuf (written after We2 consumed hbuf, dead
    // before d2's zero_k overwrites them -- all stream-ordered).
    float* c2t   = ws + 1070608;  // 512
    float* hm2t  = ws + 1071120;  // 16384
    float* hist  = ws + 1087504;  // 524288 (1024 blocks x 512 bins)
    float* sspart= ws + 1611792;  // 1024

    dim3 blk(16, 16);

    zero_k<<<dim3(2135), dim3(256), 0, stream>>>(ws, 546320);
    zero_k<<<dim3(4096), dim3(256), 0, stream>>>(hbuf, 1048576);   // We1 acc
    zero_k<<<dim3(8192), dim3(256), 0, stream>>>(o_xr, 2097152);   // Wd2 acc

    // ---- encoder ----
    gemm_big<true><<<dim3(16, 4, 8), dim3(256), 0, stream>>>(
        x, We1, hbuf, 512, 2048, 4096, 512);
    epi_k<ACT_RELU><<<dim3(4096), dim3(256), 0, stream>>>(hbuf, be1, nullptr, 512, 2048);
    gemm_big<true><<<dim3(4, 4, 32), dim3(256), 0, stream>>>(
        hbuf, We2, z0, 512, 512, 2048, 64);
    epi_k<ACT_RELU><<<dim3(1024), dim3(256), 0, stream>>>(z0, be2, nullptr, 512, 512);
    gemm_acc<<<dim3(1, 8, 32), blk, 0, stream>>>(z0, Wre1, t1, 512, 16, 512, 16);
    epi_k<ACT_RELU><<<dim3(32), dim3(256), 0, stream>>>(t1, bre1, nullptr, 512, 16);
    gemm_fused<ACT_RESBN><<<dim3(8, 8), blk, 0, stream>>>(
        t1, Wre2, bre2, zencf, o_zenc, z0, ge, bebn, 512, 512, 16);

    // ---- vector quantizer ----
    esq2_k<<<dim3(2), dim3(256), 0, stream>>>(E, bt2, Wt2, c2t, hm2t);
    vqc_k<<<dim3(1024), dim3(256), 0, stream>>>(zencf, Wt1, bt1, bt2, Wt2, E,
                                                c2t, hm2t, o_q, hist, sspart);
    finalize_k<<<dim3(1), dim3(512), 0, stream>>>(hist, sspart, out);

    // ---- classifier head ----
    gemm_acc<<<dim3(1, 8, 32), blk, 0, stream>>>(o_q, Wc, clsf, 512, 10, 32768, 1024);
    epi_k<ACT_SIGMOID><<<dim3(20), dim3(256), 0, stream>>>(clsf, bc, o_cls, 512, 10);

    // ---- decoder ----
    gemm_big<false><<<dim3(4, 4, 32), dim3(256), 0, stream>>>(
        o_q, Wp, dp0, 512, 512, 32768, 1024);               // o_q is 8B-aligned!
    epi_k<ACT_RELU><<<dim3(1024), dim3(256), 0, stream>>>(dp0, bp, nullptr, 512, 512);
    gemm_acc<<<dim3(1, 8, 32), blk, 0, stream>>>(dp0, Wrd1, t2, 512, 16, 512, 16);
    epi_k<ACT_RELU><<<dim3(32), dim3(256), 0, stream>>>(t2, brd1, nullptr, 512, 16);
    gemm_fused<ACT_RESBN><<<dim3(8, 8), blk, 0, stream>>>(
        t2, Wrd2, brd2, dd, nullptr, dp0, gd, bdbn, 512, 512, 16);
    zero_k<<<dim3(4096), dim3(256), 0, stream>>>(d2, 1048576);     // Wd1 acc
    gemm_big<true><<<dim3(16, 4, 8), dim3(256), 0, stream>>>(
        dd, Wd1, d2, 512, 2048, 512, 64);
    epi_k<ACT_RELU><<<dim3(4096), dim3(256), 0, stream>>>(d2, bd1, nullptr, 512, 2048);
    gemm_big<true><<<dim3(32, 4, 4), dim3(256), 0, stream>>>(
        d2, Wd2, o_xr, 512, 4096, 2048, 512);
    epi_k<ACT_RELU><<<dim3(8192), dim3(256), 0, stream>>>(o_xr, bd2, nullptr, 512, 4096);
}